// Round 1
// baseline (560.861 us; speedup 1.0000x reference)
//
#include <hip/hip_runtime.h>
#include <hip/hip_bf16.h>

#define NMAX 64

// One wave (64 lanes) per batch: Jonker-Volgenant LAP (exact float64 replica of
// the numpy reference) + fused masked-BCE loss epilogue.
// lane j owns column (j+1) [1-based]: registers v, minv, way, p, used.
// u (row duals) in LDS: scatter updates hit distinct rows (matching property).
__global__ __launch_bounds__(64) void hung_loss_kernel(
    const float* __restrict__ pred, const float* __restrict__ gt,
    const int* __restrict__ n1s, const int* __restrict__ n2s,
    double* __restrict__ partial)
{
    const int b = blockIdx.x;
    const int lane = threadIdx.x & 63;
    const int jj = lane + 1;                       // 1-based column index
    const float* __restrict__ predb = pred + (size_t)b * NMAX * NMAX;
    const float* __restrict__ gtb   = gt   + (size_t)b * NMAX * NMAX;
    const int n1 = n1s[b];
    const int n2 = n2s[b];
    const bool trans = (n1 > n2);                  // lap requires n <= m
    const int n = trans ? n2 : n1;
    const int m = trans ? n1 : n2;
    const double INF = 1e18;

    __shared__ double u_lds[NMAX + 1];
    u_lds[lane] = 0.0;
    if (lane == 0) u_lds[NMAX] = 0.0;
    __syncthreads();

    double v = 0.0;   // column dual (lane-owned)
    int p = 0;        // row matched to this column (1-based), 0 = free

    for (int i = 1; i <= n; ++i) {
        int j0 = 0;
        double minv = INF;
        int way = 0;
        bool used = (jj > m);                      // nonexistent columns never selected
        while (true) {
            if (j0 > 0 && lane == j0 - 1) used = true;   // used[j0] = True
            const int i0 = (j0 == 0) ? i : __shfl(p, j0 - 1);   // i0 = p[j0]
            const double u_i0 = u_lds[i0];
            const int r = i0 - 1;
            const float pv = trans ? predb[lane * NMAX + r] : predb[r * NMAX + lane];
            const double aij = -(double)pv;              // a = -scores (minimize)
            if (!used) {
                const double cur = (aij - u_i0) - v;     // same assoc. as numpy
                if (cur < minv) { minv = cur; way = j0; }
            }
            // argmin over free columns, tie -> lowest index (np.argmin semantics)
            double bestv = used ? INF : minv;
            int bestj = jj;
            #pragma unroll
            for (int off = 32; off >= 1; off >>= 1) {
                const double ov = __shfl_xor(bestv, off);
                const int    oj = __shfl_xor(bestj, off);
                if (ov < bestv || (ov == bestv && oj < bestj)) { bestv = ov; bestj = oj; }
            }
            const double delta = bestv;
            const int j1 = bestj;
            // dual updates: used cols -> u[p[j]] += d, v[j] -= d; free -> minv -= d
            if (used) {
                if (p > 0) u_lds[p] += delta;            // distinct rows, no collision
                v -= delta;
            } else {
                minv -= delta;
            }
            if (lane == 0) u_lds[i] += delta;            // j0=0 entry: u[p[0]] = u[i]
            j0 = j1;
            const int pj1 = __shfl(p, j1 - 1);
            if (pj1 == 0) break;                          // reached a free column
        }
        // augment along way[] back to column 0
        while (j0 > 0) {
            const int j1w = __shfl(way, j0 - 1);
            const int newp = (j1w == 0) ? i : __shfl(p, j1w - 1);
            if (lane == j0 - 1) p = newp;
            j0 = j1w;
        }
    }

    // ---- fused loss: dis[i][j] from lane-held p; BCE in f32 like reference ----
    double lsum = 0.0;
    for (int i2 = 0; i2 < NMAX; ++i2) {
        const float pv = predb[i2 * NMAX + lane];
        const float gv = gtb[i2 * NMAX + lane];
        float dis;
        if (!trans) {
            dis = (p == i2 + 1) ? 1.0f : 0.0f;           // col lane matched to row p-1
        } else {
            const int pi = __shfl(p, i2);                // lap-col i2+1 == scores-row i2
            dis = (pi - 1 == lane) ? 1.0f : 0.0f;
        }
        float ali = dis + gv;
        if (ali > 1.0f) ali = 0.9f;
        const float pp = ali * pv;
        const float gg = ali * gv;
        const float lp  = fmaxf(logf(pp),    -100.0f);   // clip(log(p), -100)
        const float l1p = fmaxf(log1pf(-pp), -100.0f);   // clip(log1p(-p), -100)
        const float bce = -(gg * lp + (1.0f - gg) * l1p);
        if (i2 < n1 && lane < n2) lsum += (double)bce;
    }
    #pragma unroll
    for (int off = 32; off >= 1; off >>= 1) lsum += __shfl_xor(lsum, off);
    if (lane == 0) partial[b] = lsum;
}

__global__ __launch_bounds__(256) void finalize_kernel(
    const double* __restrict__ partial, const int* __restrict__ n1s,
    float* __restrict__ out, int B)
{
    __shared__ double sred[256];
    __shared__ int    nred[256];
    const int t = threadIdx.x;
    double s = 0.0;
    int ns = 0;
    for (int bb = t; bb < B; bb += 256) { s += partial[bb]; ns += n1s[bb]; }
    sred[t] = s; nred[t] = ns;
    __syncthreads();
    for (int off = 128; off >= 1; off >>= 1) {
        if (t < off) { sred[t] += sred[t + off]; nred[t] += nred[t + off]; }
        __syncthreads();
    }
    if (t == 0) out[0] = (float)sred[0] / (float)nred[0];
}

extern "C" void kernel_launch(void* const* d_in, const int* in_sizes, int n_in,
                              void* d_out, int out_size, void* d_ws, size_t ws_size,
                              hipStream_t stream) {
    const float* pred = (const float*)d_in[0];   // [B,64,64] f32
    const float* gt   = (const float*)d_in[1];   // [B,64,64] f32
    const int* n1s    = (const int*)d_in[2];     // [B] i32
    const int* n2s    = (const int*)d_in[3];     // [B] i32
    float* out = (float*)d_out;                  // scalar f32
    double* partial = (double*)d_ws;             // B doubles (16 KB)
    const int B = in_sizes[2];

    hung_loss_kernel<<<B, 64, 0, stream>>>(pred, gt, n1s, n2s, partial);
    finalize_kernel<<<1, 256, 0, stream>>>(partial, n1s, out, B);
}

// Round 2
// 300.302 us; speedup vs baseline: 1.8677x; 1.8677x over previous
//
#include <hip/hip_runtime.h>
#include <hip/hip_bf16.h>

#define NMAX 64
#define LDA 65   // +1 pad: conflict-free row and column access

// One wave (64 lanes) per batch: Jonker-Volgenant LAP, exact float64 replica of
// the numpy reference, + fused masked-BCE loss epilogue.
// lane j owns column j+1 (v, minv, way, p, used); lane r owns row-dual u[r+1].
// Cost matrix staged in padded LDS (pre-transposed when n1 > n2).
__global__ __launch_bounds__(64) void hung_loss_kernel(
    const float* __restrict__ pred, const float* __restrict__ gt,
    const int* __restrict__ n1s, const int* __restrict__ n2s,
    double* __restrict__ partial)
{
    const int b = blockIdx.x;
    const int lane = threadIdx.x & 63;
    const int jj = lane + 1;                       // 1-based column index
    const float* __restrict__ predb = pred + (size_t)b * NMAX * NMAX;
    const float* __restrict__ gtb   = gt   + (size_t)b * NMAX * NMAX;
    const int n1 = n1s[b];
    const int n2 = n2s[b];
    const bool trans = (n1 > n2);                  // lap requires n <= m
    const int n = trans ? n2 : n1;
    const int m = trans ? n1 : n2;
    const double INF = 1e18;

    // ---- stage cost matrix into LDS (lap layout: a_lds[r*LDA+c] = scores[LAP r][LAP c]) ----
    __shared__ float a_lds[NMAX * LDA];
    {
        const float4* p4 = (const float4*)predb;
        #pragma unroll
        for (int it = 0; it < 16; ++it) {
            const float4 val = p4[it * 64 + lane];
            const int r = it * 4 + (lane >> 4);    // source row in pred
            const int c = (lane & 15) * 4;         // source col in pred
            if (!trans) {
                a_lds[r * LDA + c + 0] = val.x;
                a_lds[r * LDA + c + 1] = val.y;
                a_lds[r * LDA + c + 2] = val.z;
                a_lds[r * LDA + c + 3] = val.w;
            } else {
                a_lds[(c + 0) * LDA + r] = val.x;
                a_lds[(c + 1) * LDA + r] = val.y;
                a_lds[(c + 2) * LDA + r] = val.z;
                a_lds[(c + 3) * LDA + r] = val.w;
            }
        }
    }
    __syncthreads();

    double u_reg = 0.0;  // lane r owns u[r+1] (row dual)
    double v = 0.0;      // lane j owns v[j+1] (column dual)
    int p = 0;           // row matched to this column (1-based), 0 = free

    for (int i = 1; i <= n; ++i) {
        int j0 = 0;
        int i0 = i;                                // i0 = p[j0]; p[0] = i
        double minv = INF;
        int way = 0;
        bool used = (jj > m);                      // fake columns never selected
        bool rowused = false;                      // lane r: row r+1 on the tree
        while (true) {
            if (j0 > 0 && lane == j0 - 1) used = true;     // used[j0] = True
            if (lane == i0 - 1) rowused = true;            // row i0 joins the tree
            const double u_i0 = __shfl(u_reg, i0 - 1);
            const double aij = -(double)a_lds[(i0 - 1) * LDA + lane];  // minimize -scores
            if (!used) {
                const double cur = (aij - u_i0) - v;       // same assoc. as numpy
                if (cur < minv) { minv = cur; way = j0; }
            }
            const double contrib = used ? INF : minv;
            double delta = contrib;
            #pragma unroll
            for (int off = 32; off >= 1; off >>= 1)
                delta = fmin(delta, __shfl_xor(delta, off));
            // argmin tie -> lowest index == np.argmin first occurrence
            const unsigned long long eqmask = __ballot(contrib == delta);
            const int j1 = __ffsll((unsigned long long)eqmask);
            // dual updates (exact per-iteration association, registers only)
            if (rowused) u_reg += delta;                   // u[p[j]] += delta (incl. u[i])
            if (used) v -= delta; else minv -= delta;
            j0 = j1;
            i0 = __shfl(p, j1 - 1);                        // p[j1]; 0 => free column
            if (i0 == 0) break;
        }
        // augment along way[] back to column 0
        while (j0 > 0) {
            const int j1w = __shfl(way, j0 - 1);
            const int newp = (j1w == 0) ? i : __shfl(p, j1w - 1);
            if (lane == j0 - 1) p = newp;
            j0 = j1w;
        }
    }

    // ---- fused loss: dis[i][j] from lane-held p; BCE in f32 like reference ----
    double lsum = 0.0;
    for (int i2 = 0; i2 < NMAX; ++i2) {
        const float pv = predb[i2 * NMAX + lane];
        const float gv = gtb[i2 * NMAX + lane];
        float dis;
        if (!trans) {
            dis = (p == i2 + 1) ? 1.0f : 0.0f;             // col lane matched to row p-1
        } else {
            const int pi = __shfl(p, i2);                  // lap-col i2+1 == scores-row i2
            dis = (pi - 1 == lane) ? 1.0f : 0.0f;
        }
        float ali = dis + gv;
        if (ali > 1.0f) ali = 0.9f;
        const float pp = ali * pv;
        const float gg = ali * gv;
        const float lp  = fmaxf(logf(pp),    -100.0f);     // clip(log(p), -100)
        const float l1p = fmaxf(log1pf(-pp), -100.0f);     // clip(log1p(-p), -100)
        const float bce = -(gg * lp + (1.0f - gg) * l1p);
        if (i2 < n1 && lane < n2) lsum += (double)bce;
    }
    #pragma unroll
    for (int off = 32; off >= 1; off >>= 1) lsum += __shfl_xor(lsum, off);
    if (lane == 0) partial[b] = lsum;
}

__global__ __launch_bounds__(256) void finalize_kernel(
    const double* __restrict__ partial, const int* __restrict__ n1s,
    float* __restrict__ out, int B)
{
    __shared__ double sred[256];
    __shared__ int    nred[256];
    const int t = threadIdx.x;
    double s = 0.0;
    int ns = 0;
    for (int bb = t; bb < B; bb += 256) { s += partial[bb]; ns += n1s[bb]; }
    sred[t] = s; nred[t] = ns;
    __syncthreads();
    for (int off = 128; off >= 1; off >>= 1) {
        if (t < off) { sred[t] += sred[t + off]; nred[t] += nred[t + off]; }
        __syncthreads();
    }
    if (t == 0) out[0] = (float)sred[0] / (float)nred[0];
}

extern "C" void kernel_launch(void* const* d_in, const int* in_sizes, int n_in,
                              void* d_out, int out_size, void* d_ws, size_t ws_size,
                              hipStream_t stream) {
    const float* pred = (const float*)d_in[0];   // [B,64,64] f32
    const float* gt   = (const float*)d_in[1];   // [B,64,64] f32
    const int* n1s    = (const int*)d_in[2];     // [B] i32
    const int* n2s    = (const int*)d_in[3];     // [B] i32
    float* out = (float*)d_out;                  // scalar f32
    double* partial = (double*)d_ws;             // B doubles (16 KB)
    const int B = in_sizes[2];

    hung_loss_kernel<<<B, 64, 0, stream>>>(pred, gt, n1s, n2s, partial);
    finalize_kernel<<<1, 256, 0, stream>>>(partial, n1s, out, B);
}

// Round 3
// 214.450 us; speedup vs baseline: 2.6153x; 1.4003x over previous
//
#include <hip/hip_runtime.h>
#include <hip/hip_bf16.h>

#define NMAX 64
#define LDA 65   // +1 pad: conflict-free row and column access

// DPP-based wave64 f64 min-reduce step: x = min(x, dpp_perm(x)).
// CTRL must be an ICE -> template parameter.
template <int CTRL>
__device__ __forceinline__ double dpp_min_step(double x) {
    const int lo = __builtin_amdgcn_update_dpp(0, __double2loint(x), CTRL, 0xF, 0xF, true);
    const int hi = __builtin_amdgcn_update_dpp(0, __double2hiint(x), CTRL, 0xF, 0xF, true);
    return fmin(x, __hiloint2double(hi, lo));
}

__device__ __forceinline__ double readlane_d(double x, int l) {
    const int lo = __builtin_amdgcn_readlane(__double2loint(x), l);
    const int hi = __builtin_amdgcn_readlane(__double2hiint(x), l);
    return __hiloint2double(hi, lo);
}

// One wave (64 lanes) per batch: Jonker-Volgenant LAP, exact float64 replica of
// the numpy reference, + fused masked-BCE loss epilogue.
// lane j owns column j+1 (v, minv, way, p, used); lane r owns row-dual u[r+1].
// All cross-lane traffic uses uniform-index v_readlane / DPP (no ds_bpermute).
__global__ __launch_bounds__(64) void hung_loss_kernel(
    const float* __restrict__ pred, const float* __restrict__ gt,
    const int* __restrict__ n1s, const int* __restrict__ n2s,
    double* __restrict__ partial)
{
    const int b = blockIdx.x;
    const int lane = threadIdx.x & 63;
    const int jj = lane + 1;                       // 1-based column index
    const float* __restrict__ predb = pred + (size_t)b * NMAX * NMAX;
    const float* __restrict__ gtb   = gt   + (size_t)b * NMAX * NMAX;
    const int n1 = n1s[b];
    const int n2 = n2s[b];
    const bool trans = (n1 > n2);                  // lap requires n <= m
    const int n = trans ? n2 : n1;
    const int m = trans ? n1 : n2;
    const double INF = 1e18;

    // ---- stage cost matrix into LDS (lap layout: a_lds[r*LDA+c] = scores[LAP r][LAP c]) ----
    __shared__ float a_lds[NMAX * LDA];
    {
        const float4* p4 = (const float4*)predb;
        #pragma unroll
        for (int it = 0; it < 16; ++it) {
            const float4 val = p4[it * 64 + lane];
            const int r = it * 4 + (lane >> 4);    // source row in pred
            const int c = (lane & 15) * 4;         // source col in pred
            if (!trans) {
                a_lds[r * LDA + c + 0] = val.x;
                a_lds[r * LDA + c + 1] = val.y;
                a_lds[r * LDA + c + 2] = val.z;
                a_lds[r * LDA + c + 3] = val.w;
            } else {
                a_lds[(c + 0) * LDA + r] = val.x;
                a_lds[(c + 1) * LDA + r] = val.y;
                a_lds[(c + 2) * LDA + r] = val.z;
                a_lds[(c + 3) * LDA + r] = val.w;
            }
        }
    }
    __syncthreads();

    double u_reg = 0.0;  // lane r owns u[r+1] (row dual)
    double v = 0.0;      // lane j owns v[j+1] (column dual)
    int p = 0;           // row matched to this column (1-based), 0 = free

    for (int i = 1; i <= n; ++i) {
        int j0 = 0;
        int i0 = i;                                // i0 = p[j0]; p[0] = i
        double minv = INF;
        int way = 0;
        bool used = (jj > m);                      // fake columns never selected
        bool rowused = false;                      // lane r: row r+1 on the tree
        while (true) {
            if (j0 > 0 && lane == j0 - 1) used = true;     // used[j0] = True
            if (lane == i0 - 1) rowused = true;            // row i0 joins the tree
            const double u_i0 = readlane_d(u_reg, i0 - 1);
            const double aij = -(double)a_lds[(i0 - 1) * LDA + lane];  // minimize -scores
            if (!used) {
                const double cur = (aij - u_i0) - v;       // same assoc. as numpy
                if (cur < minv) { minv = cur; way = j0; }
            }
            const double contrib = used ? INF : minv;
            // wave64 min via DPP: quads -> rows-of-16 -> fold rows; lane63 = global min
            double red = contrib;
            red = dpp_min_step<0xB1>(red);    // quad_perm(1,0,3,2)  xor 1
            red = dpp_min_step<0x4E>(red);    // quad_perm(2,3,0,1)  xor 2
            red = dpp_min_step<0x141>(red);   // row_half_mirror     xor 4
            red = dpp_min_step<0x140>(red);   // row_mirror          xor 8
            red = dpp_min_step<0x142>(red);   // row_bcast15 (fold row k -> k+1)
            red = dpp_min_step<0x143>(red);   // row_bcast31 (fold lower 32 -> upper)
            const double delta = readlane_d(red, 63);      // exact global min (SGPR)
            // argmin tie -> lowest index == np.argmin first occurrence
            const unsigned long long eqmask = __ballot(contrib == delta);
            const int j1 = __ffsll(eqmask);
            // dual updates (exact per-iteration association, registers only)
            if (rowused) u_reg += delta;                   // u[p[j]] += delta (incl. u[i])
            if (used) v -= delta; else minv -= delta;
            j0 = j1;
            i0 = __builtin_amdgcn_readlane(p, j1 - 1);     // p[j1]; 0 => free column
            if (i0 == 0) break;
        }
        // augment along way[] back to column 0
        while (j0 > 0) {
            const int j1w = __builtin_amdgcn_readlane(way, j0 - 1);
            const int newp = (j1w == 0) ? i : __builtin_amdgcn_readlane(p, j1w - 1);
            if (lane == j0 - 1) p = newp;
            j0 = j1w;
        }
    }

    // ---- fused loss: dis[i][j] from lane-held p; BCE in f32 like reference ----
    double lsum = 0.0;
    for (int i2 = 0; i2 < NMAX; ++i2) {
        const float pv = predb[i2 * NMAX + lane];
        const float gv = gtb[i2 * NMAX + lane];
        float dis;
        if (!trans) {
            dis = (p == i2 + 1) ? 1.0f : 0.0f;             // col lane matched to row p-1
        } else {
            const int pi = __builtin_amdgcn_readlane(p, i2);  // lap-col i2+1 == scores-row i2
            dis = (pi - 1 == lane) ? 1.0f : 0.0f;
        }
        float ali = dis + gv;
        if (ali > 1.0f) ali = 0.9f;
        const float pp = ali * pv;
        const float gg = ali * gv;
        const float lp  = fmaxf(logf(pp),    -100.0f);     // clip(log(p), -100)
        const float l1p = fmaxf(log1pf(-pp), -100.0f);     // clip(log1p(-p), -100)
        const float bce = -(gg * lp + (1.0f - gg) * l1p);
        if (i2 < n1 && lane < n2) lsum += (double)bce;
    }
    #pragma unroll
    for (int off = 32; off >= 1; off >>= 1) lsum += __shfl_xor(lsum, off);
    if (lane == 0) partial[b] = lsum;
}

__global__ __launch_bounds__(256) void finalize_kernel(
    const double* __restrict__ partial, const int* __restrict__ n1s,
    float* __restrict__ out, int B)
{
    __shared__ double sred[256];
    __shared__ int    nred[256];
    const int t = threadIdx.x;
    double s = 0.0;
    int ns = 0;
    for (int bb = t; bb < B; bb += 256) { s += partial[bb]; ns += n1s[bb]; }
    sred[t] = s; nred[t] = ns;
    __syncthreads();
    for (int off = 128; off >= 1; off >>= 1) {
        if (t < off) { sred[t] += sred[t + off]; nred[t] += nred[t + off]; }
        __syncthreads();
    }
    if (t == 0) out[0] = (float)sred[0] / (float)nred[0];
}

extern "C" void kernel_launch(void* const* d_in, const int* in_sizes, int n_in,
                              void* d_out, int out_size, void* d_ws, size_t ws_size,
                              hipStream_t stream) {
    const float* pred = (const float*)d_in[0];   // [B,64,64] f32
    const float* gt   = (const float*)d_in[1];   // [B,64,64] f32
    const int* n1s    = (const int*)d_in[2];     // [B] i32
    const int* n2s    = (const int*)d_in[3];     // [B] i32
    float* out = (float*)d_out;                  // scalar f32
    double* partial = (double*)d_ws;             // B doubles (16 KB)
    const int B = in_sizes[2];

    hung_loss_kernel<<<B, 64, 0, stream>>>(pred, gt, n1s, n2s, partial);
    finalize_kernel<<<1, 256, 0, stream>>>(partial, n1s, out, B);
}